// Round 19
// baseline (316.800 us; speedup 1.0000x reference)
//
#include <hip/hip_runtime.h>
#include <math.h>

#define B_SZ   256
#define T_SEQ  720
#define C_INN  862
#define RANK   32
#define FCUT   48
#define GOUT   96
#define KTILES 27            // ceil(862/32) for encode PCA contraction

// ws layout (float offsets):
// [0, 147456)             WmR : 36864 float4 (mix Wr, [(g*12+q)*32+r])
// [147456, 294912)        WmI : 36864 float4 (mix Wi)
// [294912, 2654208)       partF : 768 x 3072 f32 (per-block partial raw DFT, [96][32])
// [2654208, 2703360)      partg : 768 x 64 f32 (per-block stat partials: sum|sumsq)
// [2703360, 2719744)      statsg: 256 x 64 f32 (mean|sd)
// [2719744, 3506176)      OBg : 256 x 6144 bf16 shorts (iDFT B-frags)
// [5898240, 5912064)      Pswz : 27648 bf16 shorts (encode B-frags)
// [5912064, 5947392)      ftabB: 70656 bf16 shorts (fwd-DFT A-frags, 96x736)
// [5947392, 6016512)      itabB: 138240 bf16 shorts (iDFT A-frags, 720x192)
// [6016512, 6030336)      Dswz : 27648 bf16 shorts (decode B-frags, 32x864)
#define WMR_OFF    (0)
#define WMI_OFF    (147456)
#define PARTF_OFF  (294912)
#define PARTG_OFF  (2654208)
#define STATSG_OFF (2703360)
#define OBG_OFF    (2719744)
#define PSWZ_OFF   (5898240)
#define FTABB_OFF  (5912064)
#define ITABB_OFF  (5947392)
#define DSWZ_OFF   (6016512)

typedef __attribute__((ext_vector_type(8))) short bf16x8;
typedef __attribute__((ext_vector_type(4))) float f32x4;

__device__ inline short f2bf(float f) {
    union { float f; unsigned u; } v; v.f = f;
    unsigned r = (v.u + 0x7fffu + ((v.u >> 16) & 1u)) >> 16;   // RNE
    return (short)r;
}
// pack two floats -> two truncated bf16 in one u32 (1 v_perm_b32)
__device__ inline unsigned pkhi(float lo, float hi) {
    return __builtin_amdgcn_perm(__float_as_uint(hi), __float_as_uint(lo), 0x07060302u);
}
union U8 { bf16x8 v; unsigned u[4]; };

// XCD-bijective swizzle for grids divisible by 8: same-batch blocks -> same XCD
__device__ inline int swz_bid(int bid, int chunks_per_xcd) {
    return (bid & 7) * chunks_per_xcd + (bid >> 3);
}

// One prep kernel: 4 bf16 tables + Wmix relayout. 1176*256 == 264192 + 36864.
__global__ __launch_bounds__(256) void k_prep(const float* __restrict__ P,
                                              const float* __restrict__ D,
                                              const float* __restrict__ Wr,
                                              const float* __restrict__ Wi,
                                              short* __restrict__ Pswz,
                                              short* __restrict__ ftabB,
                                              short* __restrict__ itabB,
                                              short* __restrict__ Dswz,
                                              float4* __restrict__ WmR,
                                              float4* __restrict__ WmI) {
    int idx = blockIdx.x * 256 + threadIdx.x;
    const float TWO_PI = 6.28318530717958647692f;
    if (idx < 138240) {
        // iDFT A-table: A[t][k], t tiles of 16 (45), k=0..191 (6 K-steps)
        int i = idx & 7, l = (idx >> 3) & 63, rest = idx >> 9;
        int ks = rest % 6, mt = rest / 6;
        int t = mt * 16 + (l & 15);
        int k = ks * 32 + ((l >> 4) << 3) + i;
        int g = k >> 1, odd = k & 1;
        float val;
        if (g == 0) {
            val = odd ? 0.0f : 0.5f;
        } else {
            int m = (g * (720 + t)) % 1440;
            float th = TWO_PI * (float)m * (1.0f / 1440.0f);
            val = odd ? sinf(th) : cosf(th);
        }
        itabB[idx] = f2bf(val);
    } else if (idx < 138240 + 70656) {
        // fwd-DFT A-table: A[row][t], row 2f=cos / 2f+1=-sin, t=0..735 (23 K-steps)
        int j = idx - 138240;
        int i = j & 7, l = (j >> 3) & 63, rest = j >> 9;
        int ks = rest % 23, mt = rest / 23;
        int row = mt * 16 + (l & 15);
        int t = ks * 32 + ((l >> 4) << 3) + i;
        int f = row >> 1, odd = row & 1;
        float val = 0.0f;
        if (t < T_SEQ) {
            int m = (f * t) % T_SEQ;
            float th = TWO_PI * (float)m * (1.0f / 720.0f);
            val = odd ? -sinf(th) : cosf(th);
        }
        ftabB[j] = f2bf(val);
    } else if (idx < 138240 + 70656 + 27648) {
        // encode B-frags (verified round 2)
        int j = idx - 138240 - 70656;
        int i = j & 7, lane = (j >> 3) & 63, rest = j >> 9;
        int ct = rest & 1, kt = rest >> 1;
        int k = kt * 32 + ((lane >> 4) << 3) + i;
        int c = ct * 16 + (lane & 15);
        float v = (k < C_INN) ? P[k * RANK + c] : 0.0f;
        Pswz[j] = f2bf(v);
    } else if (idx < 264192) {
        // decode B-frags: tile ct in [0,54)
        int j = idx - 138240 - 70656 - 27648;
        int i = j & 7, lane = (j >> 3) & 63, ct = j >> 9;
        int k = ((lane >> 4) << 3) + i;
        int c = ct * 16 + (lane & 15);
        float v = (c < C_INN) ? D[k * C_INN + c] : 0.0f;
        Dswz[j] = f2bf(v);
    } else {
        // Wmix relayout (f32 exact)
        int j = idx - 264192;          // < 36864
        int r = j & 31;
        int q = (j >> 5) % 12;
        int g = (j >> 5) / 12;
        size_t src = ((size_t)(r * 96 + g)) * 48 + q * 4;
        WmR[(g * 12 + q) * 32 + r] = *(const float4*)(Wr + src);
        WmI[(g * 12 + q) * 32 + r] = *(const float4*)(Wi + src);
    }
}

// K1: encode + stat partials + PARTIAL raw fwd-DFT (linearity: norm fix applied later).
// 3 blocks/batch: seg0 = tiles 0..15 (kt 0..7), seg1 = 16..31 (kt 8..15), seg2 = 32..44 (+pad, kt 16..22).
// Pswz staged in LDS so B-frag reads are lgkmcnt (vmcnt queue left to x-loads only).
__global__ __launch_bounds__(512) void k_encode(const float* __restrict__ x,
                                                const short* __restrict__ Pswz,
                                                const short* __restrict__ ftabB,
                                                float* __restrict__ partF,
                                                float* __restrict__ partg) {
    __shared__ short PswzL[27648];       // 55296 B: full encode B-frag table
    __shared__ short YbL[8192];          // 16 KB: this seg's Y bf16 B-frags (8 kt x 2 ct)
    __shared__ float red[512];
    int bid = swz_bid(blockIdx.x, 96);   // same-batch blocks colocate on one XCD
    int b = bid / 3, seg = bid % 3;
    int tid = threadIdx.x, l = tid & 63, w = tid >> 6;
    int h = l >> 4, c0 = l & 15, c1 = c0 + 16;
    const float* xb = x + (size_t)b * T_SEQ * C_INN;

    // stage Pswz -> LDS (55 KB, L2-resident source), coalesced int4
    for (int i4 = tid; i4 < 3456; i4 += 512)
        ((int4*)PswzL)[i4] = ((const int4*)Pswz)[i4];

    int mtbase = seg * 16;
    int ksbase = seg * 8;
    int nks    = (seg < 2) ? 8 : 7;
    int mt0 = mtbase + w;
    int mt1 = mtbase + 8 + w;
    bool valid1 = (seg < 2) || (w < 5);      // seg2: mt1 = 40+w must be <= 44
    const float* xr0 = xb + (size_t)(mt0 * 16 + c0) * C_INN;
    const float* xr1 = valid1 ? (xb + (size_t)(mt1 * 16 + c0) * C_INN) : xr0;

    // zero the pad (mt45) fragment slots: ksl=6, lp 32..63, both ct (seg2 only)
    if (seg == 2 && tid < 128) {
        int ct = tid >> 6;
        int lp = 32 + ((tid >> 1) & 31);
        int half = tid & 1;
        short4 z; z.x = 0; z.y = 0; z.z = 0; z.w = 0;
        *(short4*)&YbL[((6 * 2 + ct) * 64 + lp) * 8 + half * 4] = z;
    }
    __syncthreads();                     // PswzL ready

    const bf16x8* pb = (const bf16x8*)PswzL;

    f32x4 acc00 = {0,0,0,0}, acc01 = {0,0,0,0};
    f32x4 acc10 = {0,0,0,0}, acc11 = {0,0,0,0};

#pragma unroll 2
    for (int kt = 0; kt < KTILES - 1; ++kt) {
        int kbase = kt * 32 + h * 8;
        float4 u00 = *(const float4*)(xr0 + kbase);
        float4 u01 = *(const float4*)(xr0 + kbase + 4);
        float4 u10 = *(const float4*)(xr1 + kbase);
        float4 u11 = *(const float4*)(xr1 + kbase + 4);
        bf16x8 b0 = pb[(kt * 2 + 0) * 64 + l];
        bf16x8 b1 = pb[(kt * 2 + 1) * 64 + l];
        U8 A0, A1;
        A0.u[0] = pkhi(u00.x, u00.y); A0.u[1] = pkhi(u00.z, u00.w);
        A0.u[2] = pkhi(u01.x, u01.y); A0.u[3] = pkhi(u01.z, u01.w);
        A1.u[0] = pkhi(u10.x, u10.y); A1.u[1] = pkhi(u10.z, u10.w);
        A1.u[2] = pkhi(u11.x, u11.y); A1.u[3] = pkhi(u11.z, u11.w);
        acc00 = __builtin_amdgcn_mfma_f32_16x16x32_bf16(A0.v, b0, acc00, 0, 0, 0);
        acc01 = __builtin_amdgcn_mfma_f32_16x16x32_bf16(A0.v, b1, acc01, 0, 0, 0);
        acc10 = __builtin_amdgcn_mfma_f32_16x16x32_bf16(A1.v, b0, acc10, 0, 0, 0);
        acc11 = __builtin_amdgcn_mfma_f32_16x16x32_bf16(A1.v, b1, acc11, 0, 0, 0);
    }
    {   // PCA tail kt=26: valid k = 832..861, guarded float2 loads
        int kbase = 832 + h * 8;
        bf16x8 b0 = pb[(26 * 2 + 0) * 64 + l];
        bf16x8 b1 = pb[(26 * 2 + 1) * 64 + l];
        const float* xrs[2] = {xr0, xr1};
        f32x4* accs[2][2] = {{&acc00,&acc01},{&acc10,&acc11}};
#pragma unroll
        for (int tt = 0; tt < 2; ++tt) {
            const float* xr = xrs[tt];
            float vals[8];
            float2 u0 = *(const float2*)(xr + kbase);
            float2 u1 = *(const float2*)(xr + kbase + 2);
            float2 u2 = *(const float2*)(xr + kbase + 4);
            vals[0] = u0.x; vals[1] = u0.y;
            vals[2] = u1.x; vals[3] = u1.y;
            vals[4] = u2.x; vals[5] = u2.y;
            if (h < 3) {
                float2 u3 = *(const float2*)(xr + kbase + 6);
                vals[6] = u3.x; vals[7] = u3.y;
            } else {
                vals[6] = 0.f; vals[7] = 0.f;
            }
            U8 A;
            A.u[0] = pkhi(vals[0], vals[1]); A.u[1] = pkhi(vals[2], vals[3]);
            A.u[2] = pkhi(vals[4], vals[5]); A.u[3] = pkhi(vals[6], vals[7]);
            *accs[tt][0] = __builtin_amdgcn_mfma_f32_16x16x32_bf16(A.v, b0, *accs[tt][0], 0, 0, 0);
            *accs[tt][1] = __builtin_amdgcn_mfma_f32_16x16x32_bf16(A.v, b1, *accs[tt][1], 0, 0, 0);
        }
    }

    // stat partials (exact f32 accs, fixed order -> deterministic)
    {
        float s0 = 0.f, q0 = 0.f, s1 = 0.f, q1 = 0.f;
#pragma unroll
        for (int j = 0; j < 4; ++j) {
            float v;
            v = acc00[j]; s0 += v; q0 += v * v;
            v = acc01[j]; s1 += v; q1 += v * v;
            if (valid1) {
                v = acc10[j]; s0 += v; q0 += v * v;
                v = acc11[j]; s1 += v; q1 += v * v;
            }
        }
        s0 += __shfl_xor(s0, 16); s0 += __shfl_xor(s0, 32);
        q0 += __shfl_xor(q0, 16); q0 += __shfl_xor(q0, 32);
        s1 += __shfl_xor(s1, 16); s1 += __shfl_xor(s1, 32);
        q1 += __shfl_xor(q1, 16); q1 += __shfl_xor(q1, 32);
        if (l < 16) {
            red[c0 * 8 + w]       = s0;
            red[c1 * 8 + w]       = s1;
            red[256 + c0 * 8 + w] = q0;
            red[256 + c1 * 8 + w] = q1;
        }
    }
    __syncthreads();
    if (tid < 32) {
        float s = 0.f;
        for (int ww = 0; ww < 8; ++ww) s += red[tid * 8 + ww];
        partg[bid * 64 + tid] = s;
    } else if (tid < 64) {
        int c = tid - 32;
        float q = 0.f;
        for (int ww = 0; ww < 8; ++ww) q += red[256 + c * 8 + ww];
        partg[bid * 64 + tid] = q;
    }

    // write RAW bf16 Y fragments to LDS (layout verified rounds 7-12)
    {
        int ibase = (h & 1) * 4;
#define WRTILEL(MT, A0v, A1v)                                                      \
        {                                                                          \
            int lp  = ((2 * (MT) + (h >> 1)) & 3) * 16 + c0;                       \
            int ksl = ((MT) >> 1) - ksbase;                                        \
            short4 w0, w1;                                                         \
            w0.x = f2bf(A0v[0]); w0.y = f2bf(A0v[1]);                              \
            w0.z = f2bf(A0v[2]); w0.w = f2bf(A0v[3]);                              \
            w1.x = f2bf(A1v[0]); w1.y = f2bf(A1v[1]);                              \
            w1.z = f2bf(A1v[2]); w1.w = f2bf(A1v[3]);                              \
            *(short4*)&YbL[((ksl * 2 + 0) * 64 + lp) * 8 + ibase] = w0;            \
            *(short4*)&YbL[((ksl * 2 + 1) * 64 + lp) * 8 + ibase] = w1;            \
        }
        WRTILEL(mt0, acc00, acc01);
        if (valid1) WRTILEL(mt1, acc10, acc11);
#undef WRTILEL
    }
    __syncthreads();

    // partial raw fwd-DFT: F_part(96x32) += ftab(:, this seg's t) @ Y_seg
    {
        float* pf = partF + (size_t)bid * 3072;
        for (int idx = w; idx < 12; idx += 8) {
            int fmt = idx >> 1, fct = idx & 1;
            f32x4 acc = {0.f, 0.f, 0.f, 0.f};
            for (int ksl = 0; ksl < nks; ++ksl) {
                bf16x8 a  = ((const bf16x8*)ftabB)[(fmt * 23 + ksbase + ksl) * 64 + l];
                bf16x8 bb = *(const bf16x8*)&YbL[((ksl * 2 + fct) * 64 + l) * 8];
                acc = __builtin_amdgcn_mfma_f32_16x16x32_bf16(a, bb, acc, 0, 0, 0);
            }
#pragma unroll
            for (int j = 0; j < 4; ++j)
                pf[(fmt * 16 + h * 4 + j) * 32 + fct * 16 + c0] = acc[j];
        }
    }
}

// K2: per-block handles TWO batches: stats -> F-reduce -> mix (Wmix loaded once, applied twice)
__global__ __launch_bounds__(512) void k_front(const float* __restrict__ partF,
                                               const float* __restrict__ partg,
                                               float* __restrict__ statsg,
                                               const float4* __restrict__ WmR,
                                               const float4* __restrict__ WmI,
                                               const float* __restrict__ brr,
                                               const float* __restrict__ bii,
                                               short* __restrict__ OBg) {
    __shared__ float Fre[2][FCUT * 32];
    __shared__ float Fim[2][FCUT * 32];
    __shared__ float meanS[2][32], istdS[2][32];
    int b0  = blockIdx.x * 2;
    int tid = threadIdx.x;

    if (tid < 64) {
        int bb = tid >> 5, r = tid & 31;
        int b = b0 + bb;
        const float* pg = partg + (size_t)b * 192;
        float s = pg[r] + pg[64 + r] + pg[128 + r];
        float q = pg[32 + r] + pg[96 + r] + pg[160 + r];
        float mean = s / 720.0f;
        float var  = (q - 720.0f * mean * mean) / 719.0f;
        float sd   = sqrtf(var + 1e-5f);
        meanS[bb][r] = mean;
        istdS[bb][r] = 1.0f / sd;
        statsg[b * 64 + r]      = mean;
        statsg[b * 64 + 32 + r] = sd;
    }
    __syncthreads();

    // reduce 3 partials; DC-fix row 0; scale by istd — both batches
    for (int bb = 0; bb < 2; ++bb) {
        const float* p0 = partF + (size_t)(b0 + bb) * 3 * 3072;
        for (int e = tid; e < 3072; e += 512) {
            int row = e >> 5, r = e & 31;
            float v = p0[e] + p0[3072 + e] + p0[6144 + e];
            if (row == 0) v -= 720.0f * meanS[bb][r];
            v *= istdS[bb][r];
            int f = row >> 1;
            if (row & 1) Fim[bb][f * 32 + r] = v;
            else         Fre[bb][f * 32 + r] = v;
        }
    }
    __syncthreads();

    // mix: load Wmix once, apply to both batches (identical per-batch FMA order)
    {
        int r = tid & 31, gg = tid >> 5;
        unsigned* OB0 = (unsigned*)(OBg + (size_t)b0 * 6144);
        unsigned* OB1 = (unsigned*)(OBg + (size_t)(b0 + 1) * 6144);
        for (int g = gg; g < GOUT; g += 16) {
            float bR = brr[r * GOUT + g];
            float bI = bii[r * GOUT + g];
            float are0 = bR, aim0 = bI, are1 = bR, aim1 = bI;
            const float4* wr4 = WmR + (size_t)g * 384 + r;
            const float4* wi4 = WmI + (size_t)g * 384 + r;
#pragma unroll 3
            for (int q = 0; q < 12; ++q) {
                float4 wr = wr4[q * 32], wi = wi4[q * 32];
                int f0 = q * 4;
                float fr, fi;
#pragma unroll
                for (int e = 0; e < 4; ++e) {
                    float wre = (e == 0) ? wr.x : (e == 1) ? wr.y : (e == 2) ? wr.z : wr.w;
                    float wie = (e == 0) ? wi.x : (e == 1) ? wi.y : (e == 2) ? wi.z : wi.w;
                    fr = Fre[0][(f0 + e) * 32 + r]; fi = Fim[0][(f0 + e) * 32 + r];
                    are0 += fr * wre - fi * wie;  aim0 += fr * wie + fi * wre;
                    fr = Fre[1][(f0 + e) * 32 + r]; fi = Fim[1][(f0 + e) * 32 + r];
                    are1 += fr * wre - fi * wie;  aim1 += fr * wie + fi * wre;
                }
            }
            int ks   = g >> 4;
            int kk   = (2 * g) & 31;          // even
            int lane = (kk >> 3) * 16 + (r & 15);
            int ct   = r >> 4;
            int off  = ((((ks * 2 + ct) * 64 + lane) * 8) + (kk & 7)) >> 1;
            OB0[off] = (unsigned)(unsigned short)f2bf(are0) | (((unsigned)(unsigned short)f2bf(-aim0)) << 16);
            OB1[off] = (unsigned)(unsigned short)f2bf(are1) | (((unsigned)(unsigned short)f2bf(-aim1)) << 16);
        }
    }
}

// K3: iDFT + denorm + decode, staging each 16-row output tile as f32 in LDS,
// then storing it as fully-contiguous nontemporal float4.
__global__ __launch_bounds__(512) void k_dec(const short* __restrict__ OBg,
                                             const float* __restrict__ statsg,
                                             const short* __restrict__ itabB,
                                             const short* __restrict__ Dswz,
                                             float* __restrict__ out) {
    __shared__ short zfrag[15 * 512];                  // 15 KB: decode A-frags per tile
    __shared__ __align__(16) float stage[16 * 862];    // 55168 B
    int bid = swz_bid(blockIdx.x, 96);   // same-batch blocks colocate on one XCD
    int b = bid / 3, seg = bid % 3;
    int tid = threadIdx.x, l = tid & 63, w = tid >> 6;   // w 0..7
    int h = l >> 4, c0 = l & 15, c1 = c0 + 16;
    const bf16x8* ob = (const bf16x8*)(OBg + (size_t)b * 6144);
    const bf16x8* db = (const bf16x8*)Dswz;
    float* outb = out + (size_t)b * T_SEQ * C_INN;

    float mu0 = statsg[b * 64 + c0], sd0 = statsg[b * 64 + 32 + c0];
    float mu1 = statsg[b * 64 + c1], sd1 = statsg[b * 64 + 32 + c1];

    int lp0 = (c0 >> 3) * 16 + h * 4;
    int lp1 = (2 + (c0 >> 3)) * 16 + h * 4;

    // Phase 1: iDFT + denorm -> per-tile A-frags in LDS
    for (int ti = w; ti < 15; ti += 8) {
        int mt = seg * 15 + ti;
        f32x4 A0 = {0.f, 0.f, 0.f, 0.f};
        f32x4 A1 = {0.f, 0.f, 0.f, 0.f};
#pragma unroll
        for (int ks = 0; ks < 6; ++ks) {
            bf16x8 a  = ((const bf16x8*)itabB)[(mt * 6 + ks) * 64 + l];
            bf16x8 b0 = ob[(ks * 2 + 0) * 64 + l];
            bf16x8 b1 = ob[(ks * 2 + 1) * 64 + l];
            A0 = __builtin_amdgcn_mfma_f32_16x16x32_bf16(a, b0, A0, 0, 0, 0);
            A1 = __builtin_amdgcn_mfma_f32_16x16x32_bf16(a, b1, A1, 0, 0, 0);
        }
        short* zf = zfrag + ti * 512;
#pragma unroll
        for (int j = 0; j < 4; ++j) {
            zf[(lp0 + j) * 8 + (l & 7)] = f2bf(A0[j] * (1.0f / 360.0f) * sd0 + mu0);
            zf[(lp1 + j) * 8 + (l & 7)] = f2bf(A1[j] * (1.0f / 360.0f) * sd1 + mu1);
        }
    }
    __syncthreads();

    // Phase 2: per tile: all waves decode disjoint ct columns -> f32 stage -> contiguous store
    for (int ti = 0; ti < 15; ++ti) {
        int mt = seg * 15 + ti;
        bf16x8 a = *(const bf16x8*)&zfrag[ti * 512 + l * 8];
        for (int ct = w; ct < 54; ct += 8) {
            bf16x8 bb = db[ct * 64 + l];
            f32x4 acc = {0.f, 0.f, 0.f, 0.f};
            acc = __builtin_amdgcn_mfma_f32_16x16x32_bf16(a, bb, acc, 0, 0, 0);
            int c = ct * 16 + c0;
            if (c < C_INN) {
#pragma unroll
                for (int j = 0; j < 4; ++j)
                    stage[(h * 4 + j) * C_INN + c] = acc[j];
            }
        }
        __syncthreads();
        // 16 rows x 862 cols are contiguous in out: 3448 nontemporal float4 streaming stores
        float* dst = outb + (size_t)mt * 16 * C_INN;
        const f32x4* sg4 = (const f32x4*)stage;
        for (int f = tid; f < 3448; f += 512)
            __builtin_nontemporal_store(sg4[f], (f32x4*)(dst + f * 4));
        __syncthreads();
    }
}

extern "C" void kernel_launch(void* const* d_in, const int* in_sizes, int n_in,
                              void* d_out, int out_size, void* d_ws, size_t ws_size,
                              hipStream_t stream) {
    const float* x   = (const float*)d_in[0];
    const float* P   = (const float*)d_in[1];
    const float* D   = (const float*)d_in[2];
    const float* Wr  = (const float*)d_in[3];
    const float* Wi  = (const float*)d_in[4];
    const float* brr = (const float*)d_in[5];
    const float* bii = (const float*)d_in[6];
    float* out = (float*)d_out;
    float* ws  = (float*)d_ws;

    float4* WmR   = (float4*)(ws + WMR_OFF);
    float4* WmI   = (float4*)(ws + WMI_OFF);
    float*  partF = ws + PARTF_OFF;
    float*  partg = ws + PARTG_OFF;
    float*  statsg= ws + STATSG_OFF;
    short*  OBg   = (short*)(ws + OBG_OFF);
    short*  Pswz  = (short*)(ws + PSWZ_OFF);
    short*  ftabB = (short*)(ws + FTABB_OFF);
    short*  itabB = (short*)(ws + ITABB_OFF);
    short*  Dswz  = (short*)(ws + DSWZ_OFF);

    k_prep<<<1176, 256, 0, stream>>>(P, D, Wr, Wi, Pswz, ftabB, itabB, Dswz, WmR, WmI);
    k_encode<<<768, 512, 0, stream>>>(x, Pswz, ftabB, partF, partg);
    k_front<<<B_SZ / 2, 512, 0, stream>>>(partF, partg, statsg, WmR, WmI, brr, bii, OBg);
    k_dec<<<768, 512, 0, stream>>>(OBg, statsg, itabB, Dswz, out);
}

// Round 20
// 306.980 us; speedup vs baseline: 1.0320x; 1.0320x over previous
//
#include <hip/hip_runtime.h>
#include <math.h>

#define B_SZ   256
#define T_SEQ  720
#define C_INN  862
#define RANK   32
#define FCUT   48
#define GOUT   96
#define KTILES 27            // ceil(862/32) for encode PCA contraction

// ws layout (float offsets):
// [0, 147456)             WmR : 36864 float4 (mix Wr, [(g*12+q)*32+r])
// [147456, 294912)        WmI : 36864 float4 (mix Wi)
// [294912, 2654208)       partF : 768 x 3072 f32 (per-block partial raw DFT, [96][32])
// [2654208, 2703360)      partg : 768 x 64 f32 (per-block stat partials: sum|sumsq)
// [2703360, 2719744)      statsg: 256 x 64 f32 (mean|sd)
// [2719744, 3506176)      OBg : 256 x 6144 bf16 shorts (iDFT B-frags)
// [5898240, 5912064)      Pswz : 27648 bf16 shorts (encode B-frags)
// [5912064, 5947392)      ftabB: 70656 bf16 shorts (fwd-DFT A-frags, 96x736)
// [5947392, 6016512)      itabB: 138240 bf16 shorts (iDFT A-frags, 720x192)
// [6016512, 6030336)      Dswz : 27648 bf16 shorts (decode B-frags, 32x864)
#define WMR_OFF    (0)
#define WMI_OFF    (147456)
#define PARTF_OFF  (294912)
#define PARTG_OFF  (2654208)
#define STATSG_OFF (2703360)
#define OBG_OFF    (2719744)
#define PSWZ_OFF   (5898240)
#define FTABB_OFF  (5912064)
#define ITABB_OFF  (5947392)
#define DSWZ_OFF   (6016512)

typedef __attribute__((ext_vector_type(8))) short bf16x8;
typedef __attribute__((ext_vector_type(4))) float f32x4;

__device__ inline short f2bf(float f) {
    union { float f; unsigned u; } v; v.f = f;
    unsigned r = (v.u + 0x7fffu + ((v.u >> 16) & 1u)) >> 16;   // RNE
    return (short)r;
}
// pack two floats -> two truncated bf16 in one u32 (1 v_perm_b32)
__device__ inline unsigned pkhi(float lo, float hi) {
    return __builtin_amdgcn_perm(__float_as_uint(hi), __float_as_uint(lo), 0x07060302u);
}
union U8 { bf16x8 v; unsigned u[4]; };

// XCD-bijective swizzle for grids divisible by 8: same-batch blocks -> same XCD
__device__ inline int swz_bid(int bid, int chunks_per_xcd) {
    return (bid & 7) * chunks_per_xcd + (bid >> 3);
}

// One prep kernel: 4 bf16 tables + Wmix relayout. 1176*256 == 264192 + 36864.
__global__ __launch_bounds__(256) void k_prep(const float* __restrict__ P,
                                              const float* __restrict__ D,
                                              const float* __restrict__ Wr,
                                              const float* __restrict__ Wi,
                                              short* __restrict__ Pswz,
                                              short* __restrict__ ftabB,
                                              short* __restrict__ itabB,
                                              short* __restrict__ Dswz,
                                              float4* __restrict__ WmR,
                                              float4* __restrict__ WmI) {
    int idx = blockIdx.x * 256 + threadIdx.x;
    const float TWO_PI = 6.28318530717958647692f;
    if (idx < 138240) {
        // iDFT A-table: A[t][k], t tiles of 16 (45), k=0..191 (6 K-steps)
        int i = idx & 7, l = (idx >> 3) & 63, rest = idx >> 9;
        int ks = rest % 6, mt = rest / 6;
        int t = mt * 16 + (l & 15);
        int k = ks * 32 + ((l >> 4) << 3) + i;
        int g = k >> 1, odd = k & 1;
        float val;
        if (g == 0) {
            val = odd ? 0.0f : 0.5f;
        } else {
            int m = (g * (720 + t)) % 1440;
            float th = TWO_PI * (float)m * (1.0f / 1440.0f);
            val = odd ? sinf(th) : cosf(th);
        }
        itabB[idx] = f2bf(val);
    } else if (idx < 138240 + 70656) {
        // fwd-DFT A-table: A[row][t], row 2f=cos / 2f+1=-sin, t=0..735 (23 K-steps)
        int j = idx - 138240;
        int i = j & 7, l = (j >> 3) & 63, rest = j >> 9;
        int ks = rest % 23, mt = rest / 23;
        int row = mt * 16 + (l & 15);
        int t = ks * 32 + ((l >> 4) << 3) + i;
        int f = row >> 1, odd = row & 1;
        float val = 0.0f;
        if (t < T_SEQ) {
            int m = (f * t) % T_SEQ;
            float th = TWO_PI * (float)m * (1.0f / 720.0f);
            val = odd ? -sinf(th) : cosf(th);
        }
        ftabB[j] = f2bf(val);
    } else if (idx < 138240 + 70656 + 27648) {
        // encode B-frags (verified round 2)
        int j = idx - 138240 - 70656;
        int i = j & 7, lane = (j >> 3) & 63, rest = j >> 9;
        int ct = rest & 1, kt = rest >> 1;
        int k = kt * 32 + ((lane >> 4) << 3) + i;
        int c = ct * 16 + (lane & 15);
        float v = (k < C_INN) ? P[k * RANK + c] : 0.0f;
        Pswz[j] = f2bf(v);
    } else if (idx < 264192) {
        // decode B-frags: tile ct in [0,54)
        int j = idx - 138240 - 70656 - 27648;
        int i = j & 7, lane = (j >> 3) & 63, ct = j >> 9;
        int k = ((lane >> 4) << 3) + i;
        int c = ct * 16 + (lane & 15);
        float v = (c < C_INN) ? D[k * C_INN + c] : 0.0f;
        Dswz[j] = f2bf(v);
    } else {
        // Wmix relayout (f32 exact)
        int j = idx - 264192;          // < 36864
        int r = j & 31;
        int q = (j >> 5) % 12;
        int g = (j >> 5) / 12;
        size_t src = ((size_t)(r * 96 + g)) * 48 + q * 4;
        WmR[(g * 12 + q) * 32 + r] = *(const float4*)(Wr + src);
        WmI[(g * 12 + q) * 32 + r] = *(const float4*)(Wi + src);
    }
}

// K1: encode + stat partials + PARTIAL raw fwd-DFT (linearity: norm fix applied later).
// 3 blocks/batch; Pswz staged in LDS (lgkm/vmcnt queue separation).
__global__ __launch_bounds__(512) void k_encode(const float* __restrict__ x,
                                                const short* __restrict__ Pswz,
                                                const short* __restrict__ ftabB,
                                                float* __restrict__ partF,
                                                float* __restrict__ partg) {
    __shared__ short PswzL[27648];       // 55296 B: full encode B-frag table
    __shared__ short YbL[8192];          // 16 KB: this seg's Y bf16 B-frags (8 kt x 2 ct)
    __shared__ float red[512];
    int bid = swz_bid(blockIdx.x, 96);   // same-batch blocks colocate on one XCD
    int b = bid / 3, seg = bid % 3;
    int tid = threadIdx.x, l = tid & 63, w = tid >> 6;
    int h = l >> 4, c0 = l & 15, c1 = c0 + 16;
    const float* xb = x + (size_t)b * T_SEQ * C_INN;

    // stage Pswz -> LDS (55 KB, L2-resident source), coalesced int4
    for (int i4 = tid; i4 < 3456; i4 += 512)
        ((int4*)PswzL)[i4] = ((const int4*)Pswz)[i4];

    int mtbase = seg * 16;
    int ksbase = seg * 8;
    int nks    = (seg < 2) ? 8 : 7;
    int mt0 = mtbase + w;
    int mt1 = mtbase + 8 + w;
    bool valid1 = (seg < 2) || (w < 5);      // seg2: mt1 = 40+w must be <= 44
    const float* xr0 = xb + (size_t)(mt0 * 16 + c0) * C_INN;
    const float* xr1 = valid1 ? (xb + (size_t)(mt1 * 16 + c0) * C_INN) : xr0;

    // zero the pad (mt45) fragment slots: ksl=6, lp 32..63, both ct (seg2 only)
    if (seg == 2 && tid < 128) {
        int ct = tid >> 6;
        int lp = 32 + ((tid >> 1) & 31);
        int half = tid & 1;
        short4 z; z.x = 0; z.y = 0; z.z = 0; z.w = 0;
        *(short4*)&YbL[((6 * 2 + ct) * 64 + lp) * 8 + half * 4] = z;
    }
    __syncthreads();                     // PswzL ready

    const bf16x8* pb = (const bf16x8*)PswzL;

    f32x4 acc00 = {0,0,0,0}, acc01 = {0,0,0,0};
    f32x4 acc10 = {0,0,0,0}, acc11 = {0,0,0,0};

#pragma unroll 2
    for (int kt = 0; kt < KTILES - 1; ++kt) {
        int kbase = kt * 32 + h * 8;
        float4 u00 = *(const float4*)(xr0 + kbase);
        float4 u01 = *(const float4*)(xr0 + kbase + 4);
        float4 u10 = *(const float4*)(xr1 + kbase);
        float4 u11 = *(const float4*)(xr1 + kbase + 4);
        bf16x8 b0 = pb[(kt * 2 + 0) * 64 + l];
        bf16x8 b1 = pb[(kt * 2 + 1) * 64 + l];
        U8 A0, A1;
        A0.u[0] = pkhi(u00.x, u00.y); A0.u[1] = pkhi(u00.z, u00.w);
        A0.u[2] = pkhi(u01.x, u01.y); A0.u[3] = pkhi(u01.z, u01.w);
        A1.u[0] = pkhi(u10.x, u10.y); A1.u[1] = pkhi(u10.z, u10.w);
        A1.u[2] = pkhi(u11.x, u11.y); A1.u[3] = pkhi(u11.z, u11.w);
        acc00 = __builtin_amdgcn_mfma_f32_16x16x32_bf16(A0.v, b0, acc00, 0, 0, 0);
        acc01 = __builtin_amdgcn_mfma_f32_16x16x32_bf16(A0.v, b1, acc01, 0, 0, 0);
        acc10 = __builtin_amdgcn_mfma_f32_16x16x32_bf16(A1.v, b0, acc10, 0, 0, 0);
        acc11 = __builtin_amdgcn_mfma_f32_16x16x32_bf16(A1.v, b1, acc11, 0, 0, 0);
    }
    {   // PCA tail kt=26: valid k = 832..861, guarded float2 loads
        int kbase = 832 + h * 8;
        bf16x8 b0 = pb[(26 * 2 + 0) * 64 + l];
        bf16x8 b1 = pb[(26 * 2 + 1) * 64 + l];
        const float* xrs[2] = {xr0, xr1};
        f32x4* accs[2][2] = {{&acc00,&acc01},{&acc10,&acc11}};
#pragma unroll
        for (int tt = 0; tt < 2; ++tt) {
            const float* xr = xrs[tt];
            float vals[8];
            float2 u0 = *(const float2*)(xr + kbase);
            float2 u1 = *(const float2*)(xr + kbase + 2);
            float2 u2 = *(const float2*)(xr + kbase + 4);
            vals[0] = u0.x; vals[1] = u0.y;
            vals[2] = u1.x; vals[3] = u1.y;
            vals[4] = u2.x; vals[5] = u2.y;
            if (h < 3) {
                float2 u3 = *(const float2*)(xr + kbase + 6);
                vals[6] = u3.x; vals[7] = u3.y;
            } else {
                vals[6] = 0.f; vals[7] = 0.f;
            }
            U8 A;
            A.u[0] = pkhi(vals[0], vals[1]); A.u[1] = pkhi(vals[2], vals[3]);
            A.u[2] = pkhi(vals[4], vals[5]); A.u[3] = pkhi(vals[6], vals[7]);
            *accs[tt][0] = __builtin_amdgcn_mfma_f32_16x16x32_bf16(A.v, b0, *accs[tt][0], 0, 0, 0);
            *accs[tt][1] = __builtin_amdgcn_mfma_f32_16x16x32_bf16(A.v, b1, *accs[tt][1], 0, 0, 0);
        }
    }

    // stat partials (exact f32 accs, fixed order -> deterministic)
    {
        float s0 = 0.f, q0 = 0.f, s1 = 0.f, q1 = 0.f;
#pragma unroll
        for (int j = 0; j < 4; ++j) {
            float v;
            v = acc00[j]; s0 += v; q0 += v * v;
            v = acc01[j]; s1 += v; q1 += v * v;
            if (valid1) {
                v = acc10[j]; s0 += v; q0 += v * v;
                v = acc11[j]; s1 += v; q1 += v * v;
            }
        }
        s0 += __shfl_xor(s0, 16); s0 += __shfl_xor(s0, 32);
        q0 += __shfl_xor(q0, 16); q0 += __shfl_xor(q0, 32);
        s1 += __shfl_xor(s1, 16); s1 += __shfl_xor(s1, 32);
        q1 += __shfl_xor(q1, 16); q1 += __shfl_xor(q1, 32);
        if (l < 16) {
            red[c0 * 8 + w]       = s0;
            red[c1 * 8 + w]       = s1;
            red[256 + c0 * 8 + w] = q0;
            red[256 + c1 * 8 + w] = q1;
        }
    }
    __syncthreads();
    if (tid < 32) {
        float s = 0.f;
        for (int ww = 0; ww < 8; ++ww) s += red[tid * 8 + ww];
        partg[bid * 64 + tid] = s;
    } else if (tid < 64) {
        int c = tid - 32;
        float q = 0.f;
        for (int ww = 0; ww < 8; ++ww) q += red[256 + c * 8 + ww];
        partg[bid * 64 + tid] = q;
    }

    // write RAW bf16 Y fragments to LDS (layout verified rounds 7-12)
    {
        int ibase = (h & 1) * 4;
#define WRTILEL(MT, A0v, A1v)                                                      \
        {                                                                          \
            int lp  = ((2 * (MT) + (h >> 1)) & 3) * 16 + c0;                       \
            int ksl = ((MT) >> 1) - ksbase;                                        \
            short4 w0, w1;                                                         \
            w0.x = f2bf(A0v[0]); w0.y = f2bf(A0v[1]);                              \
            w0.z = f2bf(A0v[2]); w0.w = f2bf(A0v[3]);                              \
            w1.x = f2bf(A1v[0]); w1.y = f2bf(A1v[1]);                              \
            w1.z = f2bf(A1v[2]); w1.w = f2bf(A1v[3]);                              \
            *(short4*)&YbL[((ksl * 2 + 0) * 64 + lp) * 8 + ibase] = w0;            \
            *(short4*)&YbL[((ksl * 2 + 1) * 64 + lp) * 8 + ibase] = w1;            \
        }
        WRTILEL(mt0, acc00, acc01);
        if (valid1) WRTILEL(mt1, acc10, acc11);
#undef WRTILEL
    }
    __syncthreads();

    // partial raw fwd-DFT: F_part(96x32) += ftab(:, this seg's t) @ Y_seg
    {
        float* pf = partF + (size_t)bid * 3072;
        for (int idx = w; idx < 12; idx += 8) {
            int fmt = idx >> 1, fct = idx & 1;
            f32x4 acc = {0.f, 0.f, 0.f, 0.f};
            for (int ksl = 0; ksl < nks; ++ksl) {
                bf16x8 a  = ((const bf16x8*)ftabB)[(fmt * 23 + ksbase + ksl) * 64 + l];
                bf16x8 bb = *(const bf16x8*)&YbL[((ksl * 2 + fct) * 64 + l) * 8];
                acc = __builtin_amdgcn_mfma_f32_16x16x32_bf16(a, bb, acc, 0, 0, 0);
            }
#pragma unroll
            for (int j = 0; j < 4; ++j)
                pf[(fmt * 16 + h * 4 + j) * 32 + fct * 16 + c0] = acc[j];
        }
    }
}

// K2: per-batch: stats finalize -> reduce partial F + DC-fix + scale -> mix -> OBg
__global__ __launch_bounds__(512) void k_front(const float* __restrict__ partF,
                                               const float* __restrict__ partg,
                                               float* __restrict__ statsg,
                                               const float4* __restrict__ WmR,
                                               const float4* __restrict__ WmI,
                                               const float* __restrict__ brr,
                                               const float* __restrict__ bii,
                                               short* __restrict__ OBg) {
    __shared__ float Fre[FCUT * 32];
    __shared__ float Fim[FCUT * 32];
    __shared__ float meanS[32], istdS[32];
    int b   = blockIdx.x;
    int tid = threadIdx.x;

    if (tid < 32) {
        const float* pg = partg + (size_t)b * 192;
        float s = pg[tid] + pg[64 + tid] + pg[128 + tid];
        float q = pg[32 + tid] + pg[96 + tid] + pg[160 + tid];
        float mean = s / 720.0f;
        float var  = (q - 720.0f * mean * mean) / 719.0f;
        float sd   = sqrtf(var + 1e-5f);
        meanS[tid] = mean;
        istdS[tid] = 1.0f / sd;
        statsg[b * 64 + tid]      = mean;
        statsg[b * 64 + 32 + tid] = sd;
    }
    __syncthreads();

    // reduce 3 partials; DC-fix row 0 (linearity: DFT(mean*1) = 720*mean at f=0 only); scale by istd
    {
        const float* p0 = partF + (size_t)b * 3 * 3072;
        for (int e = tid; e < 3072; e += 512) {
            int row = e >> 5, r = e & 31;
            float v = p0[e] + p0[3072 + e] + p0[6144 + e];
            if (row == 0) v -= 720.0f * meanS[r];
            v *= istdS[r];
            int f = row >> 1;
            if (row & 1) Fim[f * 32 + r] = v;
            else         Fre[f * 32 + r] = v;
        }
    }
    __syncthreads();

    // mix -> OBg (16 g-groups x 6 iters)
    {
        int r = tid & 31, gg = tid >> 5;
        unsigned* OBb = (unsigned*)(OBg + (size_t)b * 6144);
        for (int g = gg; g < GOUT; g += 16) {
            float are = brr[r * GOUT + g];
            float aim = bii[r * GOUT + g];
            const float4* wr4 = WmR + (size_t)g * 384 + r;
            const float4* wi4 = WmI + (size_t)g * 384 + r;
#pragma unroll 3
            for (int q = 0; q < 12; ++q) {
                float4 wr = wr4[q * 32], wi = wi4[q * 32];
                int f0 = q * 4;
                float fr, fi;
                fr = Fre[(f0 + 0) * 32 + r]; fi = Fim[(f0 + 0) * 32 + r];
                are += fr * wr.x - fi * wi.x;  aim += fr * wi.x + fi * wr.x;
                fr = Fre[(f0 + 1) * 32 + r]; fi = Fim[(f0 + 1) * 32 + r];
                are += fr * wr.y - fi * wi.y;  aim += fr * wi.y + fi * wr.y;
                fr = Fre[(f0 + 2) * 32 + r]; fi = Fim[(f0 + 2) * 32 + r];
                are += fr * wr.z - fi * wi.z;  aim += fr * wi.z + fi * wr.z;
                fr = Fre[(f0 + 3) * 32 + r]; fi = Fim[(f0 + 3) * 32 + r];
                are += fr * wr.w - fi * wi.w;  aim += fr * wi.w + fi * wr.w;
            }
            int ks   = g >> 4;
            int kk   = (2 * g) & 31;          // even
            int lane = (kk >> 3) * 16 + (r & 15);
            int ct   = r >> 4;
            unsigned lo = (unsigned short)f2bf(are);
            unsigned hi = (unsigned short)f2bf(-aim);
            OBb[((((ks * 2 + ct) * 64 + lane) * 8) + (kk & 7)) >> 1] = lo | (hi << 16);
        }
    }
}

// K3: iDFT + denorm + decode. Decode B-frags are tile-invariant -> preloaded in
// registers once (phase 2 has NO vmem loads; stores are fire-and-forget).
__global__ __launch_bounds__(512) void k_dec(const short* __restrict__ OBg,
                                             const float* __restrict__ statsg,
                                             const short* __restrict__ itabB,
                                             const short* __restrict__ Dswz,
                                             float* __restrict__ out) {
    __shared__ short zfrag[15 * 512];                  // 15 KB: decode A-frags per tile
    __shared__ __align__(16) float stage[16 * 862];    // 55168 B
    int bid = swz_bid(blockIdx.x, 96);   // same-batch blocks colocate on one XCD
    int b = bid / 3, seg = bid % 3;
    int tid = threadIdx.x, l = tid & 63, w = tid >> 6;   // w 0..7
    int h = l >> 4, c0 = l & 15, c1 = c0 + 16;
    const bf16x8* ob = (const bf16x8*)(OBg + (size_t)b * 6144);
    const bf16x8* db = (const bf16x8*)Dswz;
    float* outb = out + (size_t)b * T_SEQ * C_INN;

    // preload the 7 tile-invariant decode B-frags (issued early; hides under phase 1)
    bool has7 = (w + 48 < 54);
    bf16x8 dbr0 = db[(w + 0)  * 64 + l];
    bf16x8 dbr1 = db[(w + 8)  * 64 + l];
    bf16x8 dbr2 = db[(w + 16) * 64 + l];
    bf16x8 dbr3 = db[(w + 24) * 64 + l];
    bf16x8 dbr4 = db[(w + 32) * 64 + l];
    bf16x8 dbr5 = db[(w + 40) * 64 + l];
    bf16x8 dbr6 = db[(has7 ? (w + 48) : (w + 0)) * 64 + l];

    float mu0 = statsg[b * 64 + c0], sd0 = statsg[b * 64 + 32 + c0];
    float mu1 = statsg[b * 64 + c1], sd1 = statsg[b * 64 + 32 + c1];

    int lp0 = (c0 >> 3) * 16 + h * 4;
    int lp1 = (2 + (c0 >> 3)) * 16 + h * 4;

    // Phase 1: iDFT + denorm -> per-tile A-frags in LDS
    for (int ti = w; ti < 15; ti += 8) {
        int mt = seg * 15 + ti;
        f32x4 A0 = {0.f, 0.f, 0.f, 0.f};
        f32x4 A1 = {0.f, 0.f, 0.f, 0.f};
#pragma unroll
        for (int ks = 0; ks < 6; ++ks) {
            bf16x8 a  = ((const bf16x8*)itabB)[(mt * 6 + ks) * 64 + l];
            bf16x8 b0 = ob[(ks * 2 + 0) * 64 + l];
            bf16x8 b1 = ob[(ks * 2 + 1) * 64 + l];
            A0 = __builtin_amdgcn_mfma_f32_16x16x32_bf16(a, b0, A0, 0, 0, 0);
            A1 = __builtin_amdgcn_mfma_f32_16x16x32_bf16(a, b1, A1, 0, 0, 0);
        }
        short* zf = zfrag + ti * 512;
#pragma unroll
        for (int j = 0; j < 4; ++j) {
            zf[(lp0 + j) * 8 + (l & 7)] = f2bf(A0[j] * (1.0f / 360.0f) * sd0 + mu0);
            zf[(lp1 + j) * 8 + (l & 7)] = f2bf(A1[j] * (1.0f / 360.0f) * sd1 + mu1);
        }
    }
    __syncthreads();

    // Phase 2: per tile: decode 7 register-resident B-frags -> f32 stage -> contiguous store
#define DCT(CT, BREG)                                                              \
    {                                                                              \
        f32x4 acc = {0.f, 0.f, 0.f, 0.f};                                          \
        acc = __builtin_amdgcn_mfma_f32_16x16x32_bf16(a, BREG, acc, 0, 0, 0);      \
        int c = (CT) * 16 + c0;                                                    \
        if (c < C_INN) {                                                           \
            _Pragma("unroll")                                                      \
            for (int j = 0; j < 4; ++j)                                            \
                stage[(h * 4 + j) * C_INN + c] = acc[j];                           \
        }                                                                          \
    }
    for (int ti = 0; ti < 15; ++ti) {
        int mt = seg * 15 + ti;
        bf16x8 a = *(const bf16x8*)&zfrag[ti * 512 + l * 8];
        DCT(w + 0,  dbr0);
        DCT(w + 8,  dbr1);
        DCT(w + 16, dbr2);
        DCT(w + 24, dbr3);
        DCT(w + 32, dbr4);
        DCT(w + 40, dbr5);
        if (has7) DCT(w + 48, dbr6);
        __syncthreads();
        // 16 rows x 862 cols are contiguous in out: 3448 nontemporal float4 streaming stores
        float* dst = outb + (size_t)mt * 16 * C_INN;
        const f32x4* sg4 = (const f32x4*)stage;
        for (int f = tid; f < 3448; f += 512)
            __builtin_nontemporal_store(sg4[f], (f32x4*)(dst + f * 4));
        __syncthreads();
    }
#undef DCT
}

extern "C" void kernel_launch(void* const* d_in, const int* in_sizes, int n_in,
                              void* d_out, int out_size, void* d_ws, size_t ws_size,
                              hipStream_t stream) {
    const float* x   = (const float*)d_in[0];
    const float* P   = (const float*)d_in[1];
    const float* D   = (const float*)d_in[2];
    const float* Wr  = (const float*)d_in[3];
    const float* Wi  = (const float*)d_in[4];
    const float* brr = (const float*)d_in[5];
    const float* bii = (const float*)d_in[6];
    float* out = (float*)d_out;
    float* ws  = (float*)d_ws;

    float4* WmR   = (float4*)(ws + WMR_OFF);
    float4* WmI   = (float4*)(ws + WMI_OFF);
    float*  partF = ws + PARTF_OFF;
    float*  partg = ws + PARTG_OFF;
    float*  statsg= ws + STATSG_OFF;
    short*  OBg   = (short*)(ws + OBG_OFF);
    short*  Pswz  = (short*)(ws + PSWZ_OFF);
    short*  ftabB = (short*)(ws + FTABB_OFF);
    short*  itabB = (short*)(ws + ITABB_OFF);
    short*  Dswz  = (short*)(ws + DSWZ_OFF);

    k_prep<<<1176, 256, 0, stream>>>(P, D, Wr, Wi, Pswz, ftabB, itabB, Dswz, WmR, WmI);
    k_encode<<<768, 512, 0, stream>>>(x, Pswz, ftabB, partF, partg);
    k_front<<<B_SZ, 512, 0, stream>>>(partF, partg, statsg, WmR, WmI, brr, bii, OBg);
    k_dec<<<768, 512, 0, stream>>>(OBg, statsg, itabB, Dswz, out);
}